// Round 20
// baseline (254.559 us; speedup 1.0000x reference)
//
#include <hip/hip_runtime.h>
#include <hip/hip_bf16.h>

#define NSPEC 4
#define NFEAT 144
#define RCUT 5.0f
#define CPB 256                // centers per coarse bucket
#define MAXBC 400              // max coarse buckets (NC <= 102400)
#define CAP 5120               // pairs capacity per bucket (avg ~4600)
#define CHUNK 8192             // pairs per partition block
#define PBDIM 1024             // block threads (16 waves)
#define IPT (CHUNK / PBDIM)    // items per thread = 8
#define ASTRIDE 148            // accum stage stride (floats)
#define PLDSN (CHUNK + 2 * MAXBC + 16 + 128)

// ---------- utility ----------

__global__ void zero_f32(float* __restrict__ out, int n) {
    int n4 = n >> 2;
    float4* o4 = (float4*)out;
    for (int i = blockIdx.x * blockDim.x + threadIdx.x; i < n4; i += gridDim.x * blockDim.x)
        o4[i] = make_float4(0.f, 0.f, 0.f, 0.f);
    int tail = n & 3;
    if (blockIdx.x == 0 && threadIdx.x < tail) out[n4 * 4 + threadIdx.x] = 0.f;
}

// ---------- prep: per-chunk species counts + gCursor zeroing ----------

__global__ void prep_kernel(const int* __restrict__ cs, int n, int* __restrict__ chunkCounts,
                            int* __restrict__ zeroPtr, int zeroN) {
    __shared__ int cnt[NSPEC];
    if (threadIdx.x < NSPEC) cnt[threadIdx.x] = 0;
    __syncthreads();
    int i = blockIdx.x * blockDim.x + threadIdx.x;
    if (i < n) atomicAdd(&cnt[cs[i]], 1);
    if (zeroPtr) {
        for (int j = i; j < zeroN; j += gridDim.x * blockDim.x) zeroPtr[j] = 0;
    }
    __syncthreads();
    if (threadIdx.x < NSPEC) chunkCounts[blockIdx.x * NSPEC + threadIdx.x] = cnt[threadIdx.x];
}

// ---------- fused partition + dest kernel ----------
// blocks [0, nPart):        partition pairs into coarse center buckets (256 centers)
// blocks [nPart, +nChunks): compute dest[] for one 256-center chunk
// payload u: bits[31:10] = r (low 10 mantissa bits replaced), bits[9:2] = center&255,
// bits[1:0] = species.

__global__ void __launch_bounds__(PBDIM) partdest_kernel(
        const float* __restrict__ dirs, const int* __restrict__ pci,
        const int* __restrict__ nsi, const int* __restrict__ cs,
        const int* __restrict__ chunkCounts, int* __restrict__ dest,
        int* __restrict__ gCursor, unsigned* __restrict__ gBucket,
        int P, int NC, int nbkc, int nChunks, int nPart) {
    __shared__ int ldsraw[PLDSN];

    int tid = threadIdx.x;
    int lane = tid & 63, wv = tid >> 6;

    if ((int)blockIdx.x < nPart) {
        // ---------------- partition job ----------------
        unsigned* sSort = (unsigned*)ldsraw;          // CHUNK
        int* sHist = ldsraw + CHUNK;                  // MAXBC
        int* sOffs = sHist + MAXBC;                   // MAXBC
        int* sWaveTot = sOffs + MAXBC;                // 16

        int base = blockIdx.x * CHUNK;

        for (int i = tid; i < nbkc; i += PBDIM) sHist[i] = 0;
        __syncthreads();

        unsigned uu[IPT];
        int bb[IPT];
        #pragma unroll
        for (int j = 0; j < IPT; ++j) {
            int i = base + j * PBDIM + tid;
            int bkt = -1; unsigned u = 0;
            if (i < P) {
                float x = dirs[3 * i + 0], y = dirs[3 * i + 1], z = dirs[3 * i + 2];
                float r2 = x * x + y * y + z * z;
                if (r2 < RCUT * RCUT) {
                    float r = sqrtf(r2);
                    int c = pci[i];
                    bkt = c >> 8;
                    u = (__float_as_uint(r) & 0xFFFFFC00u) | ((unsigned)(c & 255) << 2) |
                        (unsigned)nsi[i];
                    atomicAdd(&sHist[bkt], 1);
                }
            }
            uu[j] = u; bb[j] = bkt;
        }
        __syncthreads();

        // block exclusive scan of sHist[0..nbkc) into sOffs (nbkc <= 1024)
        int run = 0;
        if (tid < nbkc) run = sHist[tid];
        int incl = run;
        #pragma unroll
        for (int off = 1; off < 64; off <<= 1) {
            int t = __shfl_up(incl, off);
            if (lane >= off) incl += t;
        }
        if (lane == 63) sWaveTot[wv] = incl;
        __syncthreads();
        int wbase = 0;
        for (int w = 0; w < wv; ++w) wbase += sWaveTot[w];
        if (tid < nbkc) sOffs[tid] = wbase + incl - run;
        __syncthreads();

        // scatter into LDS sorted order (sOffs becomes end-cursor per bucket)
        #pragma unroll
        for (int j = 0; j < IPT; ++j) {
            if (bb[j] >= 0) {
                int pos = atomicAdd(&sOffs[bb[j]], 1);
                sSort[pos] = uu[j];
            }
        }
        __syncthreads();

        // flush: WAVE-COOPERATIVE — each wave claims a bucket, 64 lanes write coalesced
        for (int b = wv; b < nbkc; b += PBDIM / 64) {
            int c = sHist[b];
            if (!c) continue;
            int start = sOffs[b] - c;
            int g = 0;
            if (lane == 0) g = atomicAdd(&gCursor[b], c);
            g = __shfl(g, 0);
            int lim = min(c, CAP - g);      // safety clamp
            unsigned* dst = gBucket + (size_t)b * CAP + g;
            for (int k = lane; k < lim; k += 64) dst[k] = sSort[start + k];
        }
    } else {
        // ---------------- dest job: chunk cj (atomic-free wave reduce) ----------------
        int cj = blockIdx.x - nPart;
        if (cj >= nChunks) return;
        int* cOffs = ldsraw;          // 4
        int* wPart = ldsraw + 8;      // 16*2
        int* spAcc = ldsraw + 48;     // 8
        int* wCnt  = ldsraw + 64;     // 16*4

        int sp = wv & 3;
        int pref = 0, tot = 0;
        for (int c = (wv >> 2) * 64 + lane; c < nChunks; c += 256) {
            int v = chunkCounts[c * NSPEC + sp];
            tot += v;
            if (c < cj) pref += v;
        }
        #pragma unroll
        for (int off = 32; off; off >>= 1) {
            pref += __shfl_down(pref, off);
            tot  += __shfl_down(tot, off);
        }
        if (lane == 0) { wPart[wv * 2] = pref; wPart[wv * 2 + 1] = tot; }
        __syncthreads();

        if (tid < 4) {
            int p = 0, t = 0;
            for (int w = tid; w < 16; w += 4) { p += wPart[w * 2]; t += wPart[w * 2 + 1]; }
            spAcc[tid] = p; spAcc[4 + tid] = t;
        }
        __syncthreads();
        if (tid == 0) {
            int b = 0;
            #pragma unroll
            for (int s = 0; s < NSPEC; ++s) { cOffs[s] = b + spAcc[s]; b += spAcc[4 + s]; }
        }
        __syncthreads();

        int i = cj * 256 + tid;
        int s = (tid < 256 && i < NC) ? cs[i] : -1;
        int lanePrefix = 0;
        #pragma unroll
        for (int spp = 0; spp < NSPEC; ++spp) {
            unsigned long long b = __ballot(s == spp);
            if (lane == 0) wCnt[wv * 4 + spp] = __popcll(b);
            if (spp == s) lanePrefix = __popcll(b & ((1ull << lane) - 1ull));
        }
        __syncthreads();
        if (s >= 0) {
            int wp = 0;
            for (int w = 0; w < wv; ++w) wp += wCnt[w * 4 + s];
            dest[i] = cOffs[s] + wp + lanePrefix;
        }
    }
}

// ---------- accumulate: coarse bucket -> LDS sort -> ONE thread per (center,species) bin ----

__global__ void __launch_bounds__(PBDIM) accum_kernel(
        const int* __restrict__ gCursor, const unsigned* __restrict__ gBucket,
        const int* __restrict__ dest, float* __restrict__ out, int NC) {
    __shared__ unsigned sSort[CAP];
    __shared__ int sHist[1024];
    __shared__ int sOff[1024];
    __shared__ int sWaveTot[16];
    __shared__ int destLds[CPB];
    __shared__ float sStage[64 * ASTRIDE];

    int tid = threadIdx.x;
    int b = blockIdx.x;
    int cBase = b * CPB;
    int n = min(gCursor[b], CAP);
    const unsigned* src = gBucket + (size_t)b * CAP;

    sHist[tid] = 0;
    if (tid < CPB && cBase + tid < NC) destLds[tid] = dest[cBase + tid];
    __syncthreads();

    // pass 1: histogram over 1024 bins (bucket run is coalesced; re-read hits L2)
    for (int i = tid; i < n; i += PBDIM) atomicAdd(&sHist[src[i] & 1023u], 1);
    __syncthreads();

    // exclusive scan of 1024 bins
    int lane = tid & 63, wv = tid >> 6;
    int v = sHist[tid];
    int incl = v;
    #pragma unroll
    for (int off = 1; off < 64; off <<= 1) {
        int t = __shfl_up(incl, off);
        if (lane >= off) incl += t;
    }
    if (lane == 63) sWaveTot[wv] = incl;
    __syncthreads();
    int wbase = 0;
    for (int w = 0; w < wv; ++w) wbase += sWaveTot[w];
    sOff[tid] = wbase + incl - v;
    __syncthreads();

    // pass 2: scatter into LDS sorted order (sOff becomes end-cursor)
    for (int i = tid; i < n; i += PBDIM) {
        unsigned u = src[i];
        int pos = atomicAdd(&sOff[u & 1023u], 1);
        sSort[pos] = u;
    }
    __syncthreads();

    // my bin = tid = (centerLocal<<2)|species
    int end = sOff[tid], start = end - sHist[tid];
    float acc[36];
    #pragma unroll
    for (int j = 0; j < 36; ++j) acc[j] = 0.f;

    for (int p = start; p < end; ++p) {
        unsigned u = sSort[p];
        float r = __uint_as_float(u & 0xFFFFFC00u);
        float r2 = r * r;
        float fc = 0.5f * (__cosf(0.6283185307179586f * r) + 1.0f);  // cos(pi*r/RCUT)
        float q = __expf(-r2 * 0.04f);                                // exp(-r^2/25)
        float q2 = q * q;
        float bq[12];  // bq[n] = q^(n+1), two independent x q^2 chains
        bq[0] = q; bq[1] = q2;
        #pragma unroll
        for (int nn = 2; nn < 12; ++nn) bq[nn] = bq[nn - 2] * q2;
        float a0 = fc, a1 = fc * r, a2 = a1 * r, a3 = a2 * r;
        #pragma unroll
        for (int nn = 0; nn < 12; ++nn) acc[nn]      = fmaf(a0, bq[nn], acc[nn]);
        #pragma unroll
        for (int nn = 0; nn < 10; ++nn) acc[12 + nn] = fmaf(a1, bq[nn], acc[12 + nn]);
        #pragma unroll
        for (int nn = 0; nn < 8; ++nn)  acc[22 + nn] = fmaf(a2, bq[nn], acc[22 + nn]);
        #pragma unroll
        for (int nn = 0; nn < 6; ++nn)  acc[30 + nn] = fmaf(a3, bq[nn], acc[30 + nn]);
    }

    // stage + write out in four 64-row groups (stage buffer holds 64 rows)
    int nRows = min(CPB, NC - cBase);
    #pragma unroll 1
    for (int g = 0; g < 4; ++g) {
        if ((tid >> 8) == g) {
            // stage my bin: row = (tid>>2)&63, col = off_l + 4n + (tid&3)
            float* rowp = sStage + ((tid >> 2) & 63) * ASTRIDE + (tid & 3);
            #pragma unroll
            for (int nn = 0; nn < 12; ++nn) rowp[nn * 4]       = acc[nn];
            #pragma unroll
            for (int nn = 0; nn < 10; ++nn) rowp[48 + nn * 4]  = acc[12 + nn];
            #pragma unroll
            for (int nn = 0; nn < 8; ++nn)  rowp[88 + nn * 4]  = acc[22 + nn];
            #pragma unroll
            for (int nn = 0; nn < 6; ++nn)  rowp[120 + nn * 4] = acc[30 + nn];
        }
        __syncthreads();
        int gRows = min(64, nRows - g * 64);
        if (gRows > 0) {
            int lim = gRows * 36;
            for (int i = tid; i < lim; i += PBDIM) {
                int row = i / 36;
                int c4 = i - row * 36;
                float4 val = *(const float4*)(sStage + row * ASTRIDE + c4 * 4);
                *(float4*)(out + (size_t)destLds[g * 64 + row] * NFEAT + c4 * 4) = val;
            }
        }
        __syncthreads();
    }
}

// ---------- fallback: direct atomic scatter ----------

__global__ void pair_kernel(const float* __restrict__ dirs,
                            const int* __restrict__ pci,
                            const int* __restrict__ nsi,
                            const int* __restrict__ dest,
                            float* __restrict__ out, int P) {
    int i = blockIdx.x * blockDim.x + threadIdx.x;
    if (i >= P) return;
    float x = dirs[3 * i + 0], y = dirs[3 * i + 1], z = dirs[3 * i + 2];
    float r2 = x * x + y * y + z * z;
    float r = sqrtf(r2);
    if (r >= RCUT) return;
    float fc = 0.5f * (cosf(3.14159265358979323846f * r * (1.0f / RCUT)) + 1.0f);
    float q = expf(-r2 * (1.0f / (RCUT * RCUT)));
    int rowb = dest[pci[i]] * NFEAT;
    int s = nsi[i];
    float* o = out + rowb + s;
    float rl = fc;
    const int nmax[4] = {12, 10, 8, 6};
    const int offl[4] = {0, 48, 88, 120};
    #pragma unroll
    for (int l = 0; l < 4; ++l) {
        float e = q;
        for (int n = 0; n < nmax[l]; ++n) { atomicAdd(o + offl[l] + n * NSPEC, rl * e); e *= q; }
        rl *= r;
    }
}

extern "C" void kernel_launch(void* const* d_in, const int* in_sizes, int n_in,
                              void* d_out, int out_size, void* d_ws, size_t ws_size,
                              hipStream_t stream) {
    const float* dirs = (const float*)d_in[0];
    const int* pci = (const int*)d_in[1];
    const int* nsi = (const int*)d_in[2];
    const int* cs = (const int*)d_in[3];
    int P = in_sizes[1];
    int NC = in_sizes[3];
    float* out = (float*)d_out;

    int nChunks = (NC + 255) / 256;
    int nbkc = (NC + CPB - 1) / CPB;
    int nPart = (P + CHUNK - 1) / CHUNK;

    // ws layout (ints)
    int* chunkCounts  = (int*)d_ws;                      // nChunks*4
    int* dest         = chunkCounts + nChunks * NSPEC;   // NC
    int* gCursor      = dest + NC;                       // nbkc
    unsigned* gBucket = (unsigned*)(gCursor + nbkc);     // nbkc*CAP

    size_t need = ((size_t)(nChunks * NSPEC) + (size_t)NC + (size_t)nbkc +
                   (size_t)nbkc * CAP) * sizeof(int);
    bool fastPath = (ws_size >= need) && (nbkc <= MAXBC);

    if (fastPath) {
        prep_kernel<<<nChunks, 256, 0, stream>>>(cs, NC, chunkCounts, gCursor, nbkc);
        partdest_kernel<<<nPart + nChunks, PBDIM, 0, stream>>>(
            dirs, pci, nsi, cs, chunkCounts, dest, gCursor, gBucket,
            P, NC, nbkc, nChunks, nPart);
        accum_kernel<<<nbkc, PBDIM, 0, stream>>>(gCursor, gBucket, dest, out, NC);
    } else {
        // fallback: prep + dest-only partdest + atomic pair scatter
        prep_kernel<<<nChunks, 256, 0, stream>>>(cs, NC, chunkCounts, (int*)nullptr, 0);
        partdest_kernel<<<nChunks, PBDIM, 0, stream>>>(
            dirs, pci, nsi, cs, chunkCounts, dest, (int*)d_ws /*unused*/, (unsigned*)d_ws,
            0 /*P=0 -> no partition blocks*/, NC, nbkc, nChunks, 0);
        zero_f32<<<2048, 256, 0, stream>>>(out, out_size);
        pair_kernel<<<(P + 255) / 256, 256, 0, stream>>>(dirs, pci, nsi, dest, out, P);
    }
}

// Round 21
// 47.664 us; speedup vs baseline: 5.3407x; 5.3407x over previous
//
#include <hip/hip_runtime.h>
#include <hip/hip_bf16.h>

#define NSPEC 4
#define NFEAT 144
#define RCUT 5.0f
#define CPB 256                // centers per coarse bucket
#define MAXBC 400              // max coarse buckets (NC <= 102400)
#define CAP 5120               // pairs capacity per bucket (avg ~4600)
#define CHUNK 8192             // pairs per partition block
#define PBDIM 1024             // block threads (16 waves)
#define IPT (CHUNK / PBDIM)    // items per thread = 8
#define ASTRIDE 148            // accum stage stride (floats)
#define PLDSN (CHUNK + 2 * MAXBC + 16 + 128)

// ---------- utility ----------

__global__ void zero_f32(float* __restrict__ out, int n) {
    int n4 = n >> 2;
    float4* o4 = (float4*)out;
    for (int i = blockIdx.x * blockDim.x + threadIdx.x; i < n4; i += gridDim.x * blockDim.x)
        o4[i] = make_float4(0.f, 0.f, 0.f, 0.f);
    int tail = n & 3;
    if (blockIdx.x == 0 && threadIdx.x < tail) out[n4 * 4 + threadIdx.x] = 0.f;
}

// ---------- prep: per-chunk species counts + gCursor zeroing ----------

__global__ void prep_kernel(const int* __restrict__ cs, int n, int* __restrict__ chunkCounts,
                            int* __restrict__ zeroPtr, int zeroN) {
    __shared__ int cnt[NSPEC];
    if (threadIdx.x < NSPEC) cnt[threadIdx.x] = 0;
    __syncthreads();
    int i = blockIdx.x * blockDim.x + threadIdx.x;
    if (i < n) atomicAdd(&cnt[cs[i]], 1);
    if (zeroPtr) {
        for (int j = i; j < zeroN; j += gridDim.x * blockDim.x) zeroPtr[j] = 0;
    }
    __syncthreads();
    if (threadIdx.x < NSPEC) chunkCounts[blockIdx.x * NSPEC + threadIdx.x] = cnt[threadIdx.x];
}

// ---------- fused partition + dest kernel ----------
// blocks [0, nPart):        partition pairs into coarse center buckets (256 centers)
// blocks [nPart, +nChunks): compute dest[] for one 256-center chunk
// payload u: bits[31:10] = r (low 10 mantissa bits replaced), bits[9:2] = center&255,
// bits[1:0] = species.

__global__ void __launch_bounds__(PBDIM) partdest_kernel(
        const float* __restrict__ dirs, const int* __restrict__ pci,
        const int* __restrict__ nsi, const int* __restrict__ cs,
        const int* __restrict__ chunkCounts, int* __restrict__ dest,
        int* __restrict__ gCursor, unsigned* __restrict__ gBucket,
        int P, int NC, int nbkc, int nChunks, int nPart) {
    __shared__ int ldsraw[PLDSN];

    int tid = threadIdx.x;
    int lane = tid & 63, wv = tid >> 6;

    if ((int)blockIdx.x < nPart) {
        // ---------------- partition job ----------------
        unsigned* sSort = (unsigned*)ldsraw;          // CHUNK
        int* sHist = ldsraw + CHUNK;                  // MAXBC
        int* sOffs = sHist + MAXBC;                   // MAXBC
        int* sWaveTot = sOffs + MAXBC;                // 16

        int base = blockIdx.x * CHUNK;

        for (int i = tid; i < nbkc; i += PBDIM) sHist[i] = 0;
        __syncthreads();

        unsigned uu[IPT];
        int bb[IPT];
        #pragma unroll
        for (int j = 0; j < IPT; ++j) {
            int i = base + j * PBDIM + tid;
            int bkt = -1; unsigned u = 0;
            if (i < P) {
                float x = dirs[3 * i + 0], y = dirs[3 * i + 1], z = dirs[3 * i + 2];
                float r2 = x * x + y * y + z * z;
                if (r2 < RCUT * RCUT) {
                    float r = sqrtf(r2);
                    int c = pci[i];
                    bkt = c >> 8;
                    u = (__float_as_uint(r) & 0xFFFFFC00u) | ((unsigned)(c & 255) << 2) |
                        (unsigned)nsi[i];
                    atomicAdd(&sHist[bkt], 1);
                }
            }
            uu[j] = u; bb[j] = bkt;
        }
        __syncthreads();

        // block exclusive scan of sHist[0..nbkc) into sOffs (nbkc <= 1024)
        int run = 0;
        if (tid < nbkc) run = sHist[tid];
        int incl = run;
        #pragma unroll
        for (int off = 1; off < 64; off <<= 1) {
            int t = __shfl_up(incl, off);
            if (lane >= off) incl += t;
        }
        if (lane == 63) sWaveTot[wv] = incl;
        __syncthreads();
        int wbase = 0;
        for (int w = 0; w < wv; ++w) wbase += sWaveTot[w];
        if (tid < nbkc) sOffs[tid] = wbase + incl - run;
        __syncthreads();

        // scatter into LDS sorted order (sOffs becomes end-cursor per bucket)
        #pragma unroll
        for (int j = 0; j < IPT; ++j) {
            if (bb[j] >= 0) {
                int pos = atomicAdd(&sOffs[bb[j]], 1);
                sSort[pos] = uu[j];
            }
        }
        __syncthreads();

        // flush each bucket's contiguous run to its global region
        for (int b = tid; b < nbkc; b += PBDIM) {
            int c = sHist[b];
            if (!c) continue;
            int start = sOffs[b] - c;
            int g = atomicAdd(&gCursor[b], c);
            int lim = min(c, CAP - g);      // safety clamp
            unsigned* dst = gBucket + (size_t)b * CAP + g;
            for (int k = 0; k < lim; ++k) dst[k] = sSort[start + k];
        }
    } else {
        // ---------------- dest job: chunk cj (atomic-free wave reduce) ----------------
        int cj = blockIdx.x - nPart;
        if (cj >= nChunks) return;
        int* cOffs = ldsraw;          // 4
        int* wPart = ldsraw + 8;      // 16*2
        int* spAcc = ldsraw + 48;     // 8
        int* wCnt  = ldsraw + 64;     // 16*4

        int sp = wv & 3;
        int pref = 0, tot = 0;
        for (int c = (wv >> 2) * 64 + lane; c < nChunks; c += 256) {
            int v = chunkCounts[c * NSPEC + sp];
            tot += v;
            if (c < cj) pref += v;
        }
        #pragma unroll
        for (int off = 32; off; off >>= 1) {
            pref += __shfl_down(pref, off);
            tot  += __shfl_down(tot, off);
        }
        if (lane == 0) { wPart[wv * 2] = pref; wPart[wv * 2 + 1] = tot; }
        __syncthreads();

        if (tid < 4) {
            int p = 0, t = 0;
            for (int w = tid; w < 16; w += 4) { p += wPart[w * 2]; t += wPart[w * 2 + 1]; }
            spAcc[tid] = p; spAcc[4 + tid] = t;
        }
        __syncthreads();
        if (tid == 0) {
            int b = 0;
            #pragma unroll
            for (int s = 0; s < NSPEC; ++s) { cOffs[s] = b + spAcc[s]; b += spAcc[4 + s]; }
        }
        __syncthreads();

        int i = cj * 256 + tid;
        int s = (tid < 256 && i < NC) ? cs[i] : -1;
        int lanePrefix = 0;
        #pragma unroll
        for (int spp = 0; spp < NSPEC; ++spp) {
            unsigned long long b = __ballot(s == spp);
            if (lane == 0) wCnt[wv * 4 + spp] = __popcll(b);
            if (spp == s) lanePrefix = __popcll(b & ((1ull << lane) - 1ull));
        }
        __syncthreads();
        if (s >= 0) {
            int wp = 0;
            for (int w = 0; w < wv; ++w) wp += wCnt[w * 4 + s];
            dest[i] = cOffs[s] + wp + lanePrefix;
        }
    }
}

// ---------- accumulate: coarse bucket -> LDS sort -> ONE thread per (center,species) bin ----

__global__ void __launch_bounds__(PBDIM) accum_kernel(
        const int* __restrict__ gCursor, const unsigned* __restrict__ gBucket,
        const int* __restrict__ dest, float* __restrict__ out, int NC) {
    __shared__ unsigned sSort[CAP];
    __shared__ int sHist[1024];
    __shared__ int sOff[1024];
    __shared__ int sWaveTot[16];
    __shared__ int destLds[CPB];
    __shared__ float sStage[64 * ASTRIDE];

    int tid = threadIdx.x;
    int b = blockIdx.x;
    int cBase = b * CPB;
    int n = min(gCursor[b], CAP);
    const unsigned* src = gBucket + (size_t)b * CAP;

    sHist[tid] = 0;
    if (tid < CPB && cBase + tid < NC) destLds[tid] = dest[cBase + tid];
    __syncthreads();

    // pass 1: histogram over 1024 bins (bucket run is coalesced; re-read hits L2)
    for (int i = tid; i < n; i += PBDIM) atomicAdd(&sHist[src[i] & 1023u], 1);
    __syncthreads();

    // exclusive scan of 1024 bins
    int lane = tid & 63, wv = tid >> 6;
    int v = sHist[tid];
    int incl = v;
    #pragma unroll
    for (int off = 1; off < 64; off <<= 1) {
        int t = __shfl_up(incl, off);
        if (lane >= off) incl += t;
    }
    if (lane == 63) sWaveTot[wv] = incl;
    __syncthreads();
    int wbase = 0;
    for (int w = 0; w < wv; ++w) wbase += sWaveTot[w];
    sOff[tid] = wbase + incl - v;
    __syncthreads();

    // pass 2: scatter into LDS sorted order (sOff becomes end-cursor)
    for (int i = tid; i < n; i += PBDIM) {
        unsigned u = src[i];
        int pos = atomicAdd(&sOff[u & 1023u], 1);
        sSort[pos] = u;
    }
    __syncthreads();

    // my bin = tid = (centerLocal<<2)|species
    int end = sOff[tid], start = end - sHist[tid];
    float acc[36];
    #pragma unroll
    for (int j = 0; j < 36; ++j) acc[j] = 0.f;

    for (int p = start; p < end; ++p) {
        unsigned u = sSort[p];
        float r = __uint_as_float(u & 0xFFFFFC00u);
        float r2 = r * r;
        float fc = 0.5f * (__cosf(0.6283185307179586f * r) + 1.0f);  // cos(pi*r/RCUT)
        float q = __expf(-r2 * 0.04f);                                // exp(-r^2/25)
        float q2 = q * q;
        float bq[12];  // bq[n] = q^(n+1), two independent x q^2 chains
        bq[0] = q; bq[1] = q2;
        #pragma unroll
        for (int nn = 2; nn < 12; ++nn) bq[nn] = bq[nn - 2] * q2;
        float a0 = fc, a1 = fc * r, a2 = a1 * r, a3 = a2 * r;
        #pragma unroll
        for (int nn = 0; nn < 12; ++nn) acc[nn]      = fmaf(a0, bq[nn], acc[nn]);
        #pragma unroll
        for (int nn = 0; nn < 10; ++nn) acc[12 + nn] = fmaf(a1, bq[nn], acc[12 + nn]);
        #pragma unroll
        for (int nn = 0; nn < 8; ++nn)  acc[22 + nn] = fmaf(a2, bq[nn], acc[22 + nn]);
        #pragma unroll
        for (int nn = 0; nn < 6; ++nn)  acc[30 + nn] = fmaf(a3, bq[nn], acc[30 + nn]);
    }

    // stage + write out in four 64-row groups (stage buffer holds 64 rows)
    int nRows = min(CPB, NC - cBase);
    #pragma unroll 1
    for (int g = 0; g < 4; ++g) {
        if ((tid >> 8) == g) {
            // stage my bin: row = (tid>>2)&63, col = off_l + 4n + (tid&3)
            float* rowp = sStage + ((tid >> 2) & 63) * ASTRIDE + (tid & 3);
            #pragma unroll
            for (int nn = 0; nn < 12; ++nn) rowp[nn * 4]       = acc[nn];
            #pragma unroll
            for (int nn = 0; nn < 10; ++nn) rowp[48 + nn * 4]  = acc[12 + nn];
            #pragma unroll
            for (int nn = 0; nn < 8; ++nn)  rowp[88 + nn * 4]  = acc[22 + nn];
            #pragma unroll
            for (int nn = 0; nn < 6; ++nn)  rowp[120 + nn * 4] = acc[30 + nn];
        }
        __syncthreads();
        int gRows = min(64, nRows - g * 64);
        if (gRows > 0) {
            int lim = gRows * 36;
            for (int i = tid; i < lim; i += PBDIM) {
                int row = i / 36;
                int c4 = i - row * 36;
                float4 val = *(const float4*)(sStage + row * ASTRIDE + c4 * 4);
                *(float4*)(out + (size_t)destLds[g * 64 + row] * NFEAT + c4 * 4) = val;
            }
        }
        __syncthreads();
    }
}

// ---------- fallback: direct atomic scatter ----------

__global__ void pair_kernel(const float* __restrict__ dirs,
                            const int* __restrict__ pci,
                            const int* __restrict__ nsi,
                            const int* __restrict__ dest,
                            float* __restrict__ out, int P) {
    int i = blockIdx.x * blockDim.x + threadIdx.x;
    if (i >= P) return;
    float x = dirs[3 * i + 0], y = dirs[3 * i + 1], z = dirs[3 * i + 2];
    float r2 = x * x + y * y + z * z;
    float r = sqrtf(r2);
    if (r >= RCUT) return;
    float fc = 0.5f * (cosf(3.14159265358979323846f * r * (1.0f / RCUT)) + 1.0f);
    float q = expf(-r2 * (1.0f / (RCUT * RCUT)));
    int rowb = dest[pci[i]] * NFEAT;
    int s = nsi[i];
    float* o = out + rowb + s;
    float rl = fc;
    const int nmax[4] = {12, 10, 8, 6};
    const int offl[4] = {0, 48, 88, 120};
    #pragma unroll
    for (int l = 0; l < 4; ++l) {
        float e = q;
        for (int n = 0; n < nmax[l]; ++n) { atomicAdd(o + offl[l] + n * NSPEC, rl * e); e *= q; }
        rl *= r;
    }
}

extern "C" void kernel_launch(void* const* d_in, const int* in_sizes, int n_in,
                              void* d_out, int out_size, void* d_ws, size_t ws_size,
                              hipStream_t stream) {
    const float* dirs = (const float*)d_in[0];
    const int* pci = (const int*)d_in[1];
    const int* nsi = (const int*)d_in[2];
    const int* cs = (const int*)d_in[3];
    int P = in_sizes[1];
    int NC = in_sizes[3];
    float* out = (float*)d_out;

    int nChunks = (NC + 255) / 256;
    int nbkc = (NC + CPB - 1) / CPB;
    int nPart = (P + CHUNK - 1) / CHUNK;

    // ws layout (ints)
    int* chunkCounts  = (int*)d_ws;                      // nChunks*4
    int* dest         = chunkCounts + nChunks * NSPEC;   // NC
    int* gCursor      = dest + NC;                       // nbkc
    unsigned* gBucket = (unsigned*)(gCursor + nbkc);     // nbkc*CAP

    size_t need = ((size_t)(nChunks * NSPEC) + (size_t)NC + (size_t)nbkc +
                   (size_t)nbkc * CAP) * sizeof(int);
    bool fastPath = (ws_size >= need) && (nbkc <= MAXBC);

    if (fastPath) {
        prep_kernel<<<nChunks, 256, 0, stream>>>(cs, NC, chunkCounts, gCursor, nbkc);
        partdest_kernel<<<nPart + nChunks, PBDIM, 0, stream>>>(
            dirs, pci, nsi, cs, chunkCounts, dest, gCursor, gBucket,
            P, NC, nbkc, nChunks, nPart);
        accum_kernel<<<nbkc, PBDIM, 0, stream>>>(gCursor, gBucket, dest, out, NC);
    } else {
        // fallback: prep + dest-only partdest + atomic pair scatter
        prep_kernel<<<nChunks, 256, 0, stream>>>(cs, NC, chunkCounts, (int*)nullptr, 0);
        partdest_kernel<<<nChunks, PBDIM, 0, stream>>>(
            dirs, pci, nsi, cs, chunkCounts, dest, (int*)d_ws /*unused*/, (unsigned*)d_ws,
            0 /*P=0 -> no partition blocks*/, NC, nbkc, nChunks, 0);
        zero_f32<<<2048, 256, 0, stream>>>(out, out_size);
        pair_kernel<<<(P + 255) / 256, 256, 0, stream>>>(dirs, pci, nsi, dest, out, P);
    }
}